// Round 5
// baseline (473.906 us; speedup 1.0000x reference)
//
#include <hip/hip_runtime.h>
#include <hip/hip_bf16.h>

typedef __attribute__((ext_vector_type(8))) short short8;
typedef __attribute__((ext_vector_type(4))) short shortx4;
typedef __attribute__((ext_vector_type(4))) float floatx4;
typedef __attribute__((ext_vector_type(16))) float floatx16;

#define N_SEQ 8192
#define M_ROWS 32768   // 4*8192

__device__ __forceinline__ unsigned short f2bf(float f) {
    unsigned int x = __builtin_bit_cast(unsigned int, f);
    x += 0x7fff + ((x >> 16) & 1);   // RNE
    return (unsigned short)(x >> 16);
}

// ---------------------------------------------------------------------------
// Kernel 0 (v2): transpose+convert 9 weight matrices [256k x 256n] fp32 ->
// bf16 Wt[job][n][k], LDS-tiled 64x64 so both read and write are coalesced.
__global__ __launch_bounds__(256) void transpose_w(
    const float* __restrict__ Wq, const float* __restrict__ Wk,
    const float* __restrict__ Wv, unsigned short* __restrict__ Wt)
{
    __shared__ unsigned short tile[64][72];
    int job = blockIdx.x;
    int tt = blockIdx.y;
    int k0 = (tt >> 2) * 64, n0 = (tt & 3) * 64;
    const float* src =
        (job < 3) ? (Wq + job * 65536) :
        (job < 6) ? (Wk + (job - 3) * 65536) :
                    (Wv + (job - 6) * 65536);
    int tid = threadIdx.x;
    // phase 1: coalesced read of [k][n] tile, convert, store to LDS
    {
        int r = tid >> 2, cs = (tid & 3) * 16;
        const float* s = src + (size_t)(k0 + r) * 256 + n0 + cs;
        #pragma unroll
        for (int h = 0; h < 2; h++) {
            float4 x0 = *(const float4*)(s + h * 8);
            float4 x1 = *(const float4*)(s + h * 8 + 4);
            short8 v;
            v[0] = (short)f2bf(x0.x); v[1] = (short)f2bf(x0.y);
            v[2] = (short)f2bf(x0.z); v[3] = (short)f2bf(x0.w);
            v[4] = (short)f2bf(x1.x); v[5] = (short)f2bf(x1.y);
            v[6] = (short)f2bf(x1.z); v[7] = (short)f2bf(x1.w);
            *(short8*)&tile[r][cs + h * 8] = v;
        }
    }
    __syncthreads();
    // phase 2: gather transposed from LDS, coalesced write of [n][k]
    {
        int rn = tid >> 2, ks = (tid & 3) * 16;
        unsigned short tmp[16];
        #pragma unroll
        for (int q = 0; q < 16; q++) tmp[q] = tile[ks + q][rn];
        short8 v0, v1;
        #pragma unroll
        for (int q = 0; q < 8; q++) { v0[q] = (short)tmp[q]; v1[q] = (short)tmp[q + 8]; }
        unsigned short* dst = Wt + (size_t)job * 65536 + (size_t)(n0 + rn) * 256 + k0 + ks;
        *(short8*)dst = v0;
        *(short8*)(dst + 8) = v1;
    }
}

// ---------------------------------------------------------------------------
// Kernel 1 (v4): Q projection, column-split. Grid 1024: bid>>1 = 64-row tile,
// bid&1 = column half (3 of 6 n-tiles). 4 blocks/CU x 4 waves = 16 waves/CU.
// A = bf16(f1+p1) staged per block (adjacent col-half block re-reads via L2).
// exp -> expQ bf16 [32768][768]; colsums -> S[4][768].
__global__ __launch_bounds__(256, 4) void projq_kernel(
    const float* __restrict__ f1, const float* __restrict__ p1,
    const float* __restrict__ bq, const unsigned short* __restrict__ Wt,
    unsigned short* __restrict__ expQ, float* __restrict__ S)
{
    __shared__ __align__(16) unsigned short As[64][264];
    int m0 = (blockIdx.x >> 1) * 64;
    int ch = blockIdx.x & 1;
    int b = m0 >> 13;
    int tid = threadIdx.x;
    int lane = tid & 63, wave = tid >> 6;
    int wm = wave >> 1, wn = wave & 1;
    int quad = lane >> 4, l15 = lane & 15;

    // stage A = bf16(f1 + p1)
    {
        int row = tid >> 2, seg = tid & 3;
        const float* fr = f1 + (size_t)(m0 + row) * 256 + seg * 64;
        const float* pr = p1 + (size_t)(m0 + row) * 256 + seg * 64;
        #pragma unroll
        for (int q = 0; q < 8; q++) {
            float4 x0 = *(const float4*)(fr + q * 8);
            float4 x1 = *(const float4*)(fr + q * 8 + 4);
            float4 y0 = *(const float4*)(pr + q * 8);
            float4 y1 = *(const float4*)(pr + q * 8 + 4);
            short8 v;
            v[0] = (short)f2bf(x0.x + y0.x); v[1] = (short)f2bf(x0.y + y0.y);
            v[2] = (short)f2bf(x0.z + y0.z); v[3] = (short)f2bf(x0.w + y0.w);
            v[4] = (short)f2bf(x1.x + y1.x); v[5] = (short)f2bf(x1.y + y1.y);
            v[6] = (short)f2bf(x1.z + y1.z); v[7] = (short)f2bf(x1.w + y1.w);
            *(short8*)&As[row][seg * 64 + q * 8] = v;
        }
    }
    __syncthreads();

    for (int njl = 0; njl < 3; njl++) {
        int gnj = ch * 3 + njl;             // 0..5 over both column halves
        int j = gnj >> 1;
        int n0 = (gnj & 1) * 128;
        const unsigned short* Wj = Wt + (size_t)j * 65536;

        floatx4 acc[2][4];
        #pragma unroll
        for (int sm = 0; sm < 2; sm++)
            #pragma unroll
            for (int sn = 0; sn < 4; sn++)
                #pragma unroll
                for (int r = 0; r < 4; r++) acc[sm][sn][r] = 0.0f;

        #pragma unroll
        for (int ks = 0; ks < 8; ks++) {
            short8 af[2], bfr[4];
            #pragma unroll
            for (int sm = 0; sm < 2; sm++)
                af[sm] = *(const short8*)&As[wm * 32 + sm * 16 + l15][ks * 32 + quad * 8];
            #pragma unroll
            for (int sn = 0; sn < 4; sn++) {
                int ncol = n0 + wn * 64 + sn * 16 + l15;
                bfr[sn] = *(const short8*)(Wj + (size_t)ncol * 256 + ks * 32 + quad * 8);
            }
            #pragma unroll
            for (int sm = 0; sm < 2; sm++)
                #pragma unroll
                for (int sn = 0; sn < 4; sn++)
                    acc[sm][sn] = __builtin_amdgcn_mfma_f32_16x16x32_bf16(
                        af[sm], bfr[sn], acc[sm][sn], 0, 0, 0);
        }

        float colsum[4] = {0.f, 0.f, 0.f, 0.f};
        #pragma unroll
        for (int sm = 0; sm < 2; sm++)
            #pragma unroll
            for (int sn = 0; sn < 4; sn++) {
                float bb = bq[j * 256 + n0 + wn * 64 + sn * 16 + l15];
                #pragma unroll
                for (int r = 0; r < 4; r++) {
                    float e = __expf(acc[sm][sn][r] + bb);
                    colsum[sn] += e;
                    int row = m0 + wm * 32 + sm * 16 + quad * 4 + r;
                    int col = j * 256 + n0 + wn * 64 + sn * 16 + l15;
                    expQ[(size_t)row * 768 + col] = f2bf(e);
                }
            }
        #pragma unroll
        for (int sn = 0; sn < 4; sn++) {
            float v = colsum[sn];
            v += __shfl_xor(v, 16, 64);
            v += __shfl_xor(v, 32, 64);
            if (quad == 0)
                atomicAdd(&S[b * 768 + j * 256 + n0 + wn * 64 + sn * 16 + l15], v);
        }
    }
}

// ---------------------------------------------------------------------------
// Kernel 2 (R1 v2, best known): fused K/V projection + softmax(K) + ctx.
// Grid: 512 x 512 thr (8 waves). 3 x 64-row tiles per block. One head per
// wave. K_s/V_s parked transposed bf16 in LDS (stride 72). ctx in regs,
// fp32 atomics on flush.
__global__ __launch_bounds__(512, 4) void projkv_ctx(
    const float* __restrict__ f2, const float* __restrict__ f3, const float* __restrict__ f4,
    const float* __restrict__ p2, const float* __restrict__ p3, const float* __restrict__ p4,
    const float* __restrict__ bk, const float* __restrict__ bv,
    const unsigned short* __restrict__ Wt, float* __restrict__ ctx)
{
    __shared__ __align__(16) unsigned short sh[36864];

    int tid = threadIdx.x;
    int lane = tid & 63, wn = tid >> 6;     // 8 waves; wave wn owns head wn
    int quad = lane >> 4, l15 = lane & 15;
    int srow = tid >> 3, seg = tid & 7;     // staging: 64 rows x 8 segs

    int gbase = -1;
    int cur_ib = -1;
    const float *fin = nullptr, *pin = nullptr;
    const unsigned short *Wk_ = nullptr, *Wv_ = nullptr;
    float bkk[2] = {0.f, 0.f}, bvv[2] = {0.f, 0.f};
    floatx16 ctxacc;

    for (int j = 0; j < 3; j++) {
        int tau = blockIdx.x * 3 + j;       // global 64-row tile index, [0,1536)
        int ib = tau >> 7;                  // (i,b) pair, 128 tiles each
        if (ib != cur_ib) {
            if (gbase >= 0) {               // flush previous (i,b) accumulation
                int d = lane & 31;
                #pragma unroll
                for (int reg = 0; reg < 16; reg++) {
                    int cc = (reg & 3) + 8 * (reg >> 2) + 4 * (lane >> 5);
                    atomicAdd(&ctx[(size_t)gbase * 1024 + cc * 32 + d], ctxacc[reg]);
                }
            }
            cur_ib = ib;
            int b = ib & 3, i = ib >> 2;
            fin = ((i == 0) ? f2 : (i == 1) ? f3 : f4) + (size_t)b * N_SEQ * 256;
            pin = ((i == 0) ? p2 : (i == 1) ? p3 : p4) + (size_t)b * N_SEQ * 256;
            Wk_ = Wt + (size_t)(3 + i) * 65536;
            Wv_ = Wt + (size_t)(6 + i) * 65536;
            #pragma unroll
            for (int sn = 0; sn < 2; sn++) {
                bkk[sn] = bk[i * 256 + wn * 32 + sn * 16 + l15];
                bvv[sn] = bv[i * 256 + wn * 32 + sn * 16 + l15];
            }
            gbase = i * 32 + b * 8 + wn;
            #pragma unroll
            for (int q = 0; q < 16; q++) ctxacc[q] = 0.0f;
        }
        int m0 = (tau & 127) * 64;

        __syncthreads();   // previous tile's KT/VT reads done before staging overwrites
        // stage AK = bf16(f+p), AV = bf16(f)
        {
            const float* fr = fin + (size_t)(m0 + srow) * 256;
            const float* pr = pin + (size_t)(m0 + srow) * 256;
            #pragma unroll
            for (int q = 0; q < 4; q++) {
                int c0 = q * 64 + seg * 8;
                float4 x0 = *(const float4*)(fr + c0);
                float4 x1 = *(const float4*)(fr + c0 + 4);
                float4 y0 = *(const float4*)(pr + c0);
                float4 y1 = *(const float4*)(pr + c0 + 4);
                short8 vv, kk;
                vv[0] = (short)f2bf(x0.x); kk[0] = (short)f2bf(x0.x + y0.x);
                vv[1] = (short)f2bf(x0.y); kk[1] = (short)f2bf(x0.y + y0.y);
                vv[2] = (short)f2bf(x0.z); kk[2] = (short)f2bf(x0.z + y0.z);
                vv[3] = (short)f2bf(x0.w); kk[3] = (short)f2bf(x0.w + y0.w);
                vv[4] = (short)f2bf(x1.x); kk[4] = (short)f2bf(x1.x + y1.x);
                vv[5] = (short)f2bf(x1.y); kk[5] = (short)f2bf(x1.y + y1.y);
                vv[6] = (short)f2bf(x1.z); kk[6] = (short)f2bf(x1.z + y1.z);
                vv[7] = (short)f2bf(x1.w); kk[7] = (short)f2bf(x1.w + y1.w);
                *(short8*)&sh[srow * 264 + c0] = kk;
                *(short8*)&sh[18432 + srow * 264 + c0] = vv;
            }
        }
        __syncthreads();

        // ---- K GEMM: 64 rows x 32 cols per wave
        floatx4 acc[4][2];
        #pragma unroll
        for (int sm = 0; sm < 4; sm++)
            #pragma unroll
            for (int sn = 0; sn < 2; sn++)
                #pragma unroll
                for (int r = 0; r < 4; r++) acc[sm][sn][r] = 0.0f;
        #pragma unroll
        for (int ks = 0; ks < 8; ks++) {
            short8 af[4], bfr[2];
            #pragma unroll
            for (int sm = 0; sm < 4; sm++)
                af[sm] = *(const short8*)&sh[(sm * 16 + l15) * 264 + ks * 32 + quad * 8];
            #pragma unroll
            for (int sn = 0; sn < 2; sn++) {
                int ncol = wn * 32 + sn * 16 + l15;
                bfr[sn] = *(const short8*)(Wk_ + (size_t)ncol * 256 + ks * 32 + quad * 8);
            }
            #pragma unroll
            for (int sm = 0; sm < 4; sm++)
                #pragma unroll
                for (int sn = 0; sn < 2; sn++)
                    acc[sm][sn] = __builtin_amdgcn_mfma_f32_16x16x32_bf16(
                        af[sm], bfr[sn], acc[sm][sn], 0, 0, 0);
        }
        // per-row softmax over this wave's head (32 cols)
        #pragma unroll
        for (int sm = 0; sm < 4; sm++)
            #pragma unroll
            for (int r = 0; r < 4; r++) {
                float e0 = __expf(acc[sm][0][r] + bkk[0]);
                float e1 = __expf(acc[sm][1][r] + bkk[1]);
                float t = e0 + e1;
                t += __shfl_xor(t, 1, 64);
                t += __shfl_xor(t, 2, 64);
                t += __shfl_xor(t, 4, 64);
                t += __shfl_xor(t, 8, 64);
                float inv = 1.0f / t;
                acc[sm][0][r] = e0 * inv;
                acc[sm][1][r] = e1 * inv;
            }
        __syncthreads();   // all waves done reading AK (region0)
        // park K_s transposed: KT[col][n], packed 4 rows per ds_write_b64
        #pragma unroll
        for (int sm = 0; sm < 4; sm++)
            #pragma unroll
            for (int sn = 0; sn < 2; sn++) {
                shortx4 v;
                #pragma unroll
                for (int r = 0; r < 4; r++) v[r] = (short)f2bf(acc[sm][sn][r]);
                *(shortx4*)&sh[(wn * 32 + sn * 16 + l15) * 72 + sm * 16 + quad * 4] = v;
            }

        // ---- V GEMM from AV (region1, untouched by KT park)
        #pragma unroll
        for (int sm = 0; sm < 4; sm++)
            #pragma unroll
            for (int sn = 0; sn < 2; sn++)
                #pragma unroll
                for (int r = 0; r < 4; r++) acc[sm][sn][r] = 0.0f;
        #pragma unroll
        for (int ks = 0; ks < 8; ks++) {
            short8 af[4], bfr[2];
            #pragma unroll
            for (int sm = 0; sm < 4; sm++)
                af[sm] = *(const short8*)&sh[18432 + (sm * 16 + l15) * 264 + ks * 32 + quad * 8];
            #pragma unroll
            for (int sn = 0; sn < 2; sn++) {
                int ncol = wn * 32 + sn * 16 + l15;
                bfr[sn] = *(const short8*)(Wv_ + (size_t)ncol * 256 + ks * 32 + quad * 8);
            }
            #pragma unroll
            for (int sm = 0; sm < 4; sm++)
                #pragma unroll
                for (int sn = 0; sn < 2; sn++)
                    acc[sm][sn] = __builtin_amdgcn_mfma_f32_16x16x32_bf16(
                        af[sm], bfr[sn], acc[sm][sn], 0, 0, 0);
        }
        __syncthreads();   // all waves done reading AV (region1)
        // park V transposed (+bias): VT[col][n] (wave-local consumption)
        #pragma unroll
        for (int sm = 0; sm < 4; sm++)
            #pragma unroll
            for (int sn = 0; sn < 2; sn++) {
                shortx4 v;
                #pragma unroll
                for (int r = 0; r < 4; r++) v[r] = (short)f2bf(acc[sm][sn][r] + bvv[sn]);
                *(shortx4*)&sh[18432 + (wn * 32 + sn * 16 + l15) * 72 + sm * 16 + quad * 4] = v;
            }

        // ---- ctx for head wn: D[c][d] += sum_n K_s[n][c] * V_s[n][d]
        {
            int hc = wn * 32 + (lane & 31);
            int nb = (lane >> 5) * 8;
            #pragma unroll
            for (int s = 0; s < 4; s++) {
                short8 afr  = *(const short8*)&sh[hc * 72 + s * 16 + nb];
                short8 bfr2 = *(const short8*)&sh[18432 + hc * 72 + s * 16 + nb];
                ctxacc = __builtin_amdgcn_mfma_f32_32x32x16_bf16(afr, bfr2, ctxacc, 0, 0, 0);
            }
        }
    }

    // final flush
    if (gbase >= 0) {
        int d = lane & 31;
        #pragma unroll
        for (int reg = 0; reg < 16; reg++) {
            int cc = (reg & 3) + 8 * (reg >> 2) + 4 * (lane >> 5);
            atomicAdd(&ctx[(size_t)gbase * 1024 + cc * 32 + d], ctxacc[reg]);
        }
    }
}

// ---------------------------------------------------------------------------
// Kernel 3: Wtld[b][e][i*256+h*32+c] = sum_d (ctx[g][c][d]/S[b][i*256+h*32+c]) * Wrp[i*256+h*32+d][e]
__global__ __launch_bounds__(256) void wtilde_kernel(
    const float* __restrict__ ctx, const float* __restrict__ S,
    const float* __restrict__ Wrp, unsigned short* __restrict__ Wtld)
{
    __shared__ float cp[1024];
    int g = blockIdx.x;  // i*32 + b*8 + h
    int i = g >> 5, b = (g >> 3) & 3, h = g & 7;
    int t = threadIdx.x;
    #pragma unroll
    for (int q = 0; q < 4; q++) {
        int idx = t + q * 256;
        int c = idx >> 5;
        cp[idx] = ctx[(size_t)g * 1024 + idx] / S[b * 768 + i * 256 + h * 32 + c];
    }
    __syncthreads();
    float accv[32];
    #pragma unroll
    for (int c = 0; c < 32; c++) accv[c] = 0.0f;
    for (int d = 0; d < 32; d++) {
        float w = Wrp[(size_t)(i * 256 + h * 32 + d) * 256 + t];
        #pragma unroll
        for (int c = 0; c < 32; c++) accv[c] += cp[c * 32 + d] * w;
    }
    for (int c = 0; c < 32; c++)
        Wtld[((size_t)b * 256 + t) * 768 + i * 256 + h * 32 + c] = f2bf(accv[c]);
}

// ---------------------------------------------------------------------------
// Kernel 4 (v4): out[b] = expQ[b] @ Wtld[b]^T + brp. Column-split grid 1024:
// bid>>1 = 64-row tile, bid&1 = 128-col half. 4 waves: wm 32-row half,
// wn 64-col half (acc[2][4]). LDS 9.2 KB -> 4 blocks/CU x 4 waves = 16 w/CU.
__global__ __launch_bounds__(256, 4) void out_kernel(
    const unsigned short* __restrict__ expQ, const unsigned short* __restrict__ Wtld,
    const float* __restrict__ brp, float* __restrict__ outp)
{
    __shared__ __align__(16) unsigned short As[64][72];
    int m0 = (blockIdx.x >> 1) * 64;
    int n0 = (blockIdx.x & 1) * 128;
    int b = m0 >> 13;
    const unsigned short* Wb = Wtld + (size_t)b * 256 * 768;
    int tid = threadIdx.x;
    int lane = tid & 63, wave = tid >> 6;
    int wm = wave >> 1, wn = wave & 1;
    int quad = lane >> 4, l15 = lane & 15;
    int srow = tid >> 2, kc0 = (tid & 3) * 16;

    floatx4 acc[2][4];
    #pragma unroll
    for (int sm = 0; sm < 2; sm++)
        #pragma unroll
        for (int sn = 0; sn < 4; sn++)
            #pragma unroll
            for (int r = 0; r < 4; r++) acc[sm][sn][r] = 0.0f;

    for (int kt = 0; kt < 12; kt++) {
        __syncthreads();
        {
            size_t ga = (size_t)(m0 + srow) * 768 + kt * 64 + kc0;
            *(short8*)&As[srow][kc0]     = *(const short8*)(expQ + ga);
            *(short8*)&As[srow][kc0 + 8] = *(const short8*)(expQ + ga + 8);
        }
        __syncthreads();
        #pragma unroll
        for (int kc = 0; kc < 64; kc += 32) {
            short8 af[2], bfr[4];
            #pragma unroll
            for (int sm = 0; sm < 2; sm++)
                af[sm] = *(const short8*)&As[wm * 32 + sm * 16 + l15][kc + quad * 8];
            #pragma unroll
            for (int sn = 0; sn < 4; sn++) {
                int ncol = n0 + wn * 64 + sn * 16 + l15;
                bfr[sn] = *(const short8*)(Wb + (size_t)ncol * 768 + kt * 64 + kc + quad * 8);
            }
            #pragma unroll
            for (int sm = 0; sm < 2; sm++)
                #pragma unroll
                for (int sn = 0; sn < 4; sn++)
                    acc[sm][sn] = __builtin_amdgcn_mfma_f32_16x16x32_bf16(
                        af[sm], bfr[sn], acc[sm][sn], 0, 0, 0);
        }
    }

    float bb[4];
    #pragma unroll
    for (int sn = 0; sn < 4; sn++) bb[sn] = brp[n0 + wn * 64 + sn * 16 + l15];
    #pragma unroll
    for (int sm = 0; sm < 2; sm++)
        #pragma unroll
        for (int sn = 0; sn < 4; sn++)
            #pragma unroll
            for (int r = 0; r < 4; r++) {
                int row = m0 + wm * 32 + sm * 16 + quad * 4 + r;
                int col = n0 + wn * 64 + sn * 16 + l15;
                outp[(size_t)row * 256 + col] = acc[sm][sn][r] + bb[sn];
            }
}

// ---------------------------------------------------------------------------
extern "C" void kernel_launch(void* const* d_in, const int* in_sizes, int n_in,
                              void* d_out, int out_size, void* d_ws, size_t ws_size,
                              hipStream_t stream)
{
    (void)in_sizes; (void)n_in; (void)out_size; (void)ws_size;
    const float* f1  = (const float*)d_in[0];
    const float* f2  = (const float*)d_in[1];
    const float* f3  = (const float*)d_in[2];
    const float* f4  = (const float*)d_in[3];
    const float* p1  = (const float*)d_in[4];
    const float* p2  = (const float*)d_in[5];
    const float* p3  = (const float*)d_in[6];
    const float* p4  = (const float*)d_in[7];
    const float* Wq  = (const float*)d_in[8];
    const float* bq  = (const float*)d_in[9];
    const float* Wk  = (const float*)d_in[10];
    const float* bk  = (const float*)d_in[11];
    const float* Wv  = (const float*)d_in[12];
    const float* bv  = (const float*)d_in[13];
    const float* Wrp = (const float*)d_in[14];
    const float* brp = (const float*)d_in[15];

    // workspace layout (total ~52 MB)
    char* ws = (char*)d_ws;
    unsigned short* expQ = (unsigned short*)(ws);                 // 50,331,648
    unsigned short* Wt   = (unsigned short*)(ws + 50331648);      //  1,179,648
    unsigned short* Wtld = (unsigned short*)(ws + 51511296);      //  1,572,864
    float*          ctx  = (float*)(ws + 53084160);               //    393,216
    float*          S    = (float*)(ws + 53477376);               //     12,288

    hipMemsetAsync(ctx, 0, 393216 + 12288, stream);  // ctx + S contiguous

    transpose_w<<<dim3(9, 16), 256, 0, stream>>>(Wq, Wk, Wv, Wt);
    projq_kernel<<<dim3(1024), 256, 0, stream>>>(f1, p1, bq, Wt, expQ, S);
    projkv_ctx<<<dim3(512), 512, 0, stream>>>(f2, f3, f4, p2, p3, p4, bk, bv, Wt, ctx);
    wtilde_kernel<<<dim3(96), 256, 0, stream>>>(ctx, S, Wrp, Wtld);
    out_kernel<<<dim3(1024), 256, 0, stream>>>(expQ, Wtld, brp, (float*)d_out);
}

// Round 6
// 430.767 us; speedup vs baseline: 1.1001x; 1.1001x over previous
//
#include <hip/hip_runtime.h>
#include <hip/hip_bf16.h>

typedef __attribute__((ext_vector_type(8))) short short8;
typedef __attribute__((ext_vector_type(4))) short shortx4;
typedef __attribute__((ext_vector_type(4))) float floatx4;
typedef __attribute__((ext_vector_type(16))) float floatx16;

#define N_SEQ 8192
#define M_ROWS 32768   // 4*8192

__device__ __forceinline__ unsigned short f2bf(float f) {
    unsigned int x = __builtin_bit_cast(unsigned int, f);
    x += 0x7fff + ((x >> 16) & 1);   // RNE
    return (unsigned short)(x >> 16);
}

// ---------------------------------------------------------------------------
// Kernel 0 (v2): transpose+convert 9 weight matrices [256k x 256n] fp32 ->
// bf16 Wt[job][n][k], LDS-tiled 64x64 so both read and write are coalesced.
__global__ __launch_bounds__(256) void transpose_w(
    const float* __restrict__ Wq, const float* __restrict__ Wk,
    const float* __restrict__ Wv, unsigned short* __restrict__ Wt)
{
    __shared__ unsigned short tile[64][72];
    int job = blockIdx.x;
    int tt = blockIdx.y;
    int k0 = (tt >> 2) * 64, n0 = (tt & 3) * 64;
    const float* src =
        (job < 3) ? (Wq + job * 65536) :
        (job < 6) ? (Wk + (job - 3) * 65536) :
                    (Wv + (job - 6) * 65536);
    int tid = threadIdx.x;
    // phase 1: coalesced read of [k][n] tile, convert, store to LDS
    {
        int r = tid >> 2, cs = (tid & 3) * 16;
        const float* s = src + (size_t)(k0 + r) * 256 + n0 + cs;
        #pragma unroll
        for (int h = 0; h < 2; h++) {
            float4 x0 = *(const float4*)(s + h * 8);
            float4 x1 = *(const float4*)(s + h * 8 + 4);
            short8 v;
            v[0] = (short)f2bf(x0.x); v[1] = (short)f2bf(x0.y);
            v[2] = (short)f2bf(x0.z); v[3] = (short)f2bf(x0.w);
            v[4] = (short)f2bf(x1.x); v[5] = (short)f2bf(x1.y);
            v[6] = (short)f2bf(x1.z); v[7] = (short)f2bf(x1.w);
            *(short8*)&tile[r][cs + h * 8] = v;
        }
    }
    __syncthreads();
    // phase 2: gather transposed from LDS, coalesced write of [n][k]
    {
        int rn = tid >> 2, ks = (tid & 3) * 16;
        unsigned short tmp[16];
        #pragma unroll
        for (int q = 0; q < 16; q++) tmp[q] = tile[ks + q][rn];
        short8 v0, v1;
        #pragma unroll
        for (int q = 0; q < 8; q++) { v0[q] = (short)tmp[q]; v1[q] = (short)tmp[q + 8]; }
        unsigned short* dst = Wt + (size_t)job * 65536 + (size_t)(n0 + rn) * 256 + k0 + ks;
        *(short8*)dst = v0;
        *(short8*)(dst + 8) = v1;
    }
}

// ---------------------------------------------------------------------------
// Kernel 1 (R0/R1 best): Q projection, all 3 branches per block. A = bf16(f1+p1)
// staged in LDS once (64 rows x 256 k), then 6 n-tiles (3 branches x 128)
// computed against it. exp -> expQ bf16 [32768][768]; colsums -> S[4][768].
__global__ __launch_bounds__(256) void projq_kernel(
    const float* __restrict__ f1, const float* __restrict__ p1,
    const float* __restrict__ bq, const unsigned short* __restrict__ Wt,
    unsigned short* __restrict__ expQ, float* __restrict__ S)
{
    __shared__ __align__(16) unsigned short As[64][264];
    int m0 = blockIdx.x * 64;
    int b = m0 >> 13;
    int tid = threadIdx.x;
    int lane = tid & 63, wave = tid >> 6;
    int wm = wave >> 1, wn = wave & 1;
    int quad = lane >> 4, l15 = lane & 15;

    // stage A = bf16(f1 + p1)
    {
        int row = tid >> 2, seg = tid & 3;
        const float* fr = f1 + (size_t)(m0 + row) * 256 + seg * 64;
        const float* pr = p1 + (size_t)(m0 + row) * 256 + seg * 64;
        #pragma unroll
        for (int q = 0; q < 8; q++) {
            float4 x0 = *(const float4*)(fr + q * 8);
            float4 x1 = *(const float4*)(fr + q * 8 + 4);
            float4 y0 = *(const float4*)(pr + q * 8);
            float4 y1 = *(const float4*)(pr + q * 8 + 4);
            short8 v;
            v[0] = (short)f2bf(x0.x + y0.x); v[1] = (short)f2bf(x0.y + y0.y);
            v[2] = (short)f2bf(x0.z + y0.z); v[3] = (short)f2bf(x0.w + y0.w);
            v[4] = (short)f2bf(x1.x + y1.x); v[5] = (short)f2bf(x1.y + y1.y);
            v[6] = (short)f2bf(x1.z + y1.z); v[7] = (short)f2bf(x1.w + y1.w);
            *(short8*)&As[row][seg * 64 + q * 8] = v;
        }
    }
    __syncthreads();

    for (int nj = 0; nj < 6; nj++) {
        int j = nj >> 1;
        int n0 = (nj & 1) * 128;
        const unsigned short* Wj = Wt + (size_t)j * 65536;

        floatx4 acc[2][4];
        #pragma unroll
        for (int sm = 0; sm < 2; sm++)
            #pragma unroll
            for (int sn = 0; sn < 4; sn++)
                #pragma unroll
                for (int r = 0; r < 4; r++) acc[sm][sn][r] = 0.0f;

        #pragma unroll
        for (int ks = 0; ks < 8; ks++) {
            short8 af[2], bfr[4];
            #pragma unroll
            for (int sm = 0; sm < 2; sm++)
                af[sm] = *(const short8*)&As[wm * 32 + sm * 16 + l15][ks * 32 + quad * 8];
            #pragma unroll
            for (int sn = 0; sn < 4; sn++) {
                int ncol = n0 + wn * 64 + sn * 16 + l15;
                bfr[sn] = *(const short8*)(Wj + (size_t)ncol * 256 + ks * 32 + quad * 8);
            }
            #pragma unroll
            for (int sm = 0; sm < 2; sm++)
                #pragma unroll
                for (int sn = 0; sn < 4; sn++)
                    acc[sm][sn] = __builtin_amdgcn_mfma_f32_16x16x32_bf16(
                        af[sm], bfr[sn], acc[sm][sn], 0, 0, 0);
        }

        float colsum[4] = {0.f, 0.f, 0.f, 0.f};
        #pragma unroll
        for (int sm = 0; sm < 2; sm++)
            #pragma unroll
            for (int sn = 0; sn < 4; sn++) {
                float bb = bq[j * 256 + n0 + wn * 64 + sn * 16 + l15];
                #pragma unroll
                for (int r = 0; r < 4; r++) {
                    float e = __expf(acc[sm][sn][r] + bb);
                    colsum[sn] += e;
                    int row = m0 + wm * 32 + sm * 16 + quad * 4 + r;
                    int col = j * 256 + n0 + wn * 64 + sn * 16 + l15;
                    expQ[(size_t)row * 768 + col] = f2bf(e);
                }
            }
        #pragma unroll
        for (int sn = 0; sn < 4; sn++) {
            float v = colsum[sn];
            v += __shfl_xor(v, 16, 64);
            v += __shfl_xor(v, 32, 64);
            if (quad == 0)
                atomicAdd(&S[b * 768 + j * 256 + n0 + wn * 64 + sn * 16 + l15], v);
        }
    }
}

// ---------------------------------------------------------------------------
// Kernel 2 (R1 v2, best known): fused K/V projection + softmax(K) + ctx.
// Grid: 512 x 512 thr (8 waves). 3 x 64-row tiles per block. One head per
// wave. K_s/V_s parked transposed bf16 in LDS (stride 72). ctx in regs,
// fp32 atomics on flush.
__global__ __launch_bounds__(512, 4) void projkv_ctx(
    const float* __restrict__ f2, const float* __restrict__ f3, const float* __restrict__ f4,
    const float* __restrict__ p2, const float* __restrict__ p3, const float* __restrict__ p4,
    const float* __restrict__ bk, const float* __restrict__ bv,
    const unsigned short* __restrict__ Wt, float* __restrict__ ctx)
{
    __shared__ __align__(16) unsigned short sh[36864];

    int tid = threadIdx.x;
    int lane = tid & 63, wn = tid >> 6;     // 8 waves; wave wn owns head wn
    int quad = lane >> 4, l15 = lane & 15;
    int srow = tid >> 3, seg = tid & 7;     // staging: 64 rows x 8 segs

    int gbase = -1;
    int cur_ib = -1;
    const float *fin = nullptr, *pin = nullptr;
    const unsigned short *Wk_ = nullptr, *Wv_ = nullptr;
    float bkk[2] = {0.f, 0.f}, bvv[2] = {0.f, 0.f};
    floatx16 ctxacc;

    for (int j = 0; j < 3; j++) {
        int tau = blockIdx.x * 3 + j;       // global 64-row tile index, [0,1536)
        int ib = tau >> 7;                  // (i,b) pair, 128 tiles each
        if (ib != cur_ib) {
            if (gbase >= 0) {               // flush previous (i,b) accumulation
                int d = lane & 31;
                #pragma unroll
                for (int reg = 0; reg < 16; reg++) {
                    int cc = (reg & 3) + 8 * (reg >> 2) + 4 * (lane >> 5);
                    atomicAdd(&ctx[(size_t)gbase * 1024 + cc * 32 + d], ctxacc[reg]);
                }
            }
            cur_ib = ib;
            int b = ib & 3, i = ib >> 2;
            fin = ((i == 0) ? f2 : (i == 1) ? f3 : f4) + (size_t)b * N_SEQ * 256;
            pin = ((i == 0) ? p2 : (i == 1) ? p3 : p4) + (size_t)b * N_SEQ * 256;
            Wk_ = Wt + (size_t)(3 + i) * 65536;
            Wv_ = Wt + (size_t)(6 + i) * 65536;
            #pragma unroll
            for (int sn = 0; sn < 2; sn++) {
                bkk[sn] = bk[i * 256 + wn * 32 + sn * 16 + l15];
                bvv[sn] = bv[i * 256 + wn * 32 + sn * 16 + l15];
            }
            gbase = i * 32 + b * 8 + wn;
            #pragma unroll
            for (int q = 0; q < 16; q++) ctxacc[q] = 0.0f;
        }
        int m0 = (tau & 127) * 64;

        __syncthreads();   // previous tile's KT/VT reads done before staging overwrites
        // stage AK = bf16(f+p), AV = bf16(f)
        {
            const float* fr = fin + (size_t)(m0 + srow) * 256;
            const float* pr = pin + (size_t)(m0 + srow) * 256;
            #pragma unroll
            for (int q = 0; q < 4; q++) {
                int c0 = q * 64 + seg * 8;
                float4 x0 = *(const float4*)(fr + c0);
                float4 x1 = *(const float4*)(fr + c0 + 4);
                float4 y0 = *(const float4*)(pr + c0);
                float4 y1 = *(const float4*)(pr + c0 + 4);
                short8 vv, kk;
                vv[0] = (short)f2bf(x0.x); kk[0] = (short)f2bf(x0.x + y0.x);
                vv[1] = (short)f2bf(x0.y); kk[1] = (short)f2bf(x0.y + y0.y);
                vv[2] = (short)f2bf(x0.z); kk[2] = (short)f2bf(x0.z + y0.z);
                vv[3] = (short)f2bf(x0.w); kk[3] = (short)f2bf(x0.w + y0.w);
                vv[4] = (short)f2bf(x1.x); kk[4] = (short)f2bf(x1.x + y1.x);
                vv[5] = (short)f2bf(x1.y); kk[5] = (short)f2bf(x1.y + y1.y);
                vv[6] = (short)f2bf(x1.z); kk[6] = (short)f2bf(x1.z + y1.z);
                vv[7] = (short)f2bf(x1.w); kk[7] = (short)f2bf(x1.w + y1.w);
                *(short8*)&sh[srow * 264 + c0] = kk;
                *(short8*)&sh[18432 + srow * 264 + c0] = vv;
            }
        }
        __syncthreads();

        // ---- K GEMM: 64 rows x 32 cols per wave
        floatx4 acc[4][2];
        #pragma unroll
        for (int sm = 0; sm < 4; sm++)
            #pragma unroll
            for (int sn = 0; sn < 2; sn++)
                #pragma unroll
                for (int r = 0; r < 4; r++) acc[sm][sn][r] = 0.0f;
        #pragma unroll
        for (int ks = 0; ks < 8; ks++) {
            short8 af[4], bfr[2];
            #pragma unroll
            for (int sm = 0; sm < 4; sm++)
                af[sm] = *(const short8*)&sh[(sm * 16 + l15) * 264 + ks * 32 + quad * 8];
            #pragma unroll
            for (int sn = 0; sn < 2; sn++) {
                int ncol = wn * 32 + sn * 16 + l15;
                bfr[sn] = *(const short8*)(Wk_ + (size_t)ncol * 256 + ks * 32 + quad * 8);
            }
            #pragma unroll
            for (int sm = 0; sm < 4; sm++)
                #pragma unroll
                for (int sn = 0; sn < 2; sn++)
                    acc[sm][sn] = __builtin_amdgcn_mfma_f32_16x16x32_bf16(
                        af[sm], bfr[sn], acc[sm][sn], 0, 0, 0);
        }
        // per-row softmax over this wave's head (32 cols)
        #pragma unroll
        for (int sm = 0; sm < 4; sm++)
            #pragma unroll
            for (int r = 0; r < 4; r++) {
                float e0 = __expf(acc[sm][0][r] + bkk[0]);
                float e1 = __expf(acc[sm][1][r] + bkk[1]);
                float t = e0 + e1;
                t += __shfl_xor(t, 1, 64);
                t += __shfl_xor(t, 2, 64);
                t += __shfl_xor(t, 4, 64);
                t += __shfl_xor(t, 8, 64);
                float inv = 1.0f / t;
                acc[sm][0][r] = e0 * inv;
                acc[sm][1][r] = e1 * inv;
            }
        __syncthreads();   // all waves done reading AK (region0)
        // park K_s transposed: KT[col][n], packed 4 rows per ds_write_b64
        #pragma unroll
        for (int sm = 0; sm < 4; sm++)
            #pragma unroll
            for (int sn = 0; sn < 2; sn++) {
                shortx4 v;
                #pragma unroll
                for (int r = 0; r < 4; r++) v[r] = (short)f2bf(acc[sm][sn][r]);
                *(shortx4*)&sh[(wn * 32 + sn * 16 + l15) * 72 + sm * 16 + quad * 4] = v;
            }

        // ---- V GEMM from AV (region1, untouched by KT park)
        #pragma unroll
        for (int sm = 0; sm < 4; sm++)
            #pragma unroll
            for (int sn = 0; sn < 2; sn++)
                #pragma unroll
                for (int r = 0; r < 4; r++) acc[sm][sn][r] = 0.0f;
        #pragma unroll
        for (int ks = 0; ks < 8; ks++) {
            short8 af[4], bfr[2];
            #pragma unroll
            for (int sm = 0; sm < 4; sm++)
                af[sm] = *(const short8*)&sh[18432 + (sm * 16 + l15) * 264 + ks * 32 + quad * 8];
            #pragma unroll
            for (int sn = 0; sn < 2; sn++) {
                int ncol = wn * 32 + sn * 16 + l15;
                bfr[sn] = *(const short8*)(Wv_ + (size_t)ncol * 256 + ks * 32 + quad * 8);
            }
            #pragma unroll
            for (int sm = 0; sm < 4; sm++)
                #pragma unroll
                for (int sn = 0; sn < 2; sn++)
                    acc[sm][sn] = __builtin_amdgcn_mfma_f32_16x16x32_bf16(
                        af[sm], bfr[sn], acc[sm][sn], 0, 0, 0);
        }
        __syncthreads();   // all waves done reading AV (region1)
        // park V transposed (+bias): VT[col][n] (wave-local consumption)
        #pragma unroll
        for (int sm = 0; sm < 4; sm++)
            #pragma unroll
            for (int sn = 0; sn < 2; sn++) {
                shortx4 v;
                #pragma unroll
                for (int r = 0; r < 4; r++) v[r] = (short)f2bf(acc[sm][sn][r] + bvv[sn]);
                *(shortx4*)&sh[18432 + (wn * 32 + sn * 16 + l15) * 72 + sm * 16 + quad * 4] = v;
            }

        // ---- ctx for head wn: D[c][d] += sum_n K_s[n][c] * V_s[n][d]
        {
            int hc = wn * 32 + (lane & 31);
            int nb = (lane >> 5) * 8;
            #pragma unroll
            for (int s = 0; s < 4; s++) {
                short8 afr  = *(const short8*)&sh[hc * 72 + s * 16 + nb];
                short8 bfr2 = *(const short8*)&sh[18432 + hc * 72 + s * 16 + nb];
                ctxacc = __builtin_amdgcn_mfma_f32_32x32x16_bf16(afr, bfr2, ctxacc, 0, 0, 0);
            }
        }
    }

    // final flush
    if (gbase >= 0) {
        int d = lane & 31;
        #pragma unroll
        for (int reg = 0; reg < 16; reg++) {
            int cc = (reg & 3) + 8 * (reg >> 2) + 4 * (lane >> 5);
            atomicAdd(&ctx[(size_t)gbase * 1024 + cc * 32 + d], ctxacc[reg]);
        }
    }
}

// ---------------------------------------------------------------------------
// Kernel 3: Wtld[b][e][i*256+h*32+c] = sum_d (ctx[g][c][d]/S[b][i*256+h*32+c]) * Wrp[i*256+h*32+d][e]
__global__ __launch_bounds__(256) void wtilde_kernel(
    const float* __restrict__ ctx, const float* __restrict__ S,
    const float* __restrict__ Wrp, unsigned short* __restrict__ Wtld)
{
    __shared__ float cp[1024];
    int g = blockIdx.x;  // i*32 + b*8 + h
    int i = g >> 5, b = (g >> 3) & 3, h = g & 7;
    int t = threadIdx.x;
    #pragma unroll
    for (int q = 0; q < 4; q++) {
        int idx = t + q * 256;
        int c = idx >> 5;
        cp[idx] = ctx[(size_t)g * 1024 + idx] / S[b * 768 + i * 256 + h * 32 + c];
    }
    __syncthreads();
    float accv[32];
    #pragma unroll
    for (int c = 0; c < 32; c++) accv[c] = 0.0f;
    for (int d = 0; d < 32; d++) {
        float w = Wrp[(size_t)(i * 256 + h * 32 + d) * 256 + t];
        #pragma unroll
        for (int c = 0; c < 32; c++) accv[c] += cp[c * 32 + d] * w;
    }
    for (int c = 0; c < 32; c++)
        Wtld[((size_t)b * 256 + t) * 768 + i * 256 + h * 32 + c] = f2bf(accv[c]);
}

// ---------------------------------------------------------------------------
// Kernel 4 (v5): out[b] = expQ[b] @ Wtld[b]^T + brp. R0 tile shape (128x128,
// grid (256,2), 256 thr) + double-buffered LDS pipeline: kt+1's expQ loads
// issue into regs BEFORE kt's MFMA phase (in flight across it), ds_write to
// the alternate buffer after, ONE barrier per kt (was two). LDS 73.7 KB.
__global__ __launch_bounds__(256) void out_kernel(
    const unsigned short* __restrict__ expQ, const unsigned short* __restrict__ Wtld,
    const float* __restrict__ brp, float* __restrict__ outp)
{
    __shared__ __align__(16) unsigned short As[2][128][72];
    int m0 = blockIdx.x * 128;
    int n0 = blockIdx.y * 128;
    int b = m0 >> 13;
    const unsigned short* Wb = Wtld + (size_t)b * 256 * 768;
    int tid = threadIdx.x;
    int lane = tid & 63, wave = tid >> 6;
    int wm = wave >> 1, wn = wave & 1;
    int quad = lane >> 4, l15 = lane & 15;
    int sr = tid >> 3, skc = (tid & 7) * 8;   // staging map: 32 rows x 64 cols per p

    floatx4 acc[4][4];
    #pragma unroll
    for (int a = 0; a < 4; a++)
        #pragma unroll
        for (int cc = 0; cc < 4; cc++)
            #pragma unroll
            for (int r = 0; r < 4; r++) acc[a][cc][r] = 0.0f;

    // prologue: stage kt=0 into buffer 0
    {
        short8 st0, st1, st2, st3;
        st0 = *(const short8*)(expQ + (size_t)(m0 + sr +  0) * 768 + skc);
        st1 = *(const short8*)(expQ + (size_t)(m0 + sr + 32) * 768 + skc);
        st2 = *(const short8*)(expQ + (size_t)(m0 + sr + 64) * 768 + skc);
        st3 = *(const short8*)(expQ + (size_t)(m0 + sr + 96) * 768 + skc);
        *(short8*)&As[0][sr +  0][skc] = st0;
        *(short8*)&As[0][sr + 32][skc] = st1;
        *(short8*)&As[0][sr + 64][skc] = st2;
        *(short8*)&As[0][sr + 96][skc] = st3;
    }
    __syncthreads();

    int cur = 0;
    for (int kt = 0; kt < 12; kt++) {
        // issue next tile's global loads; they stay in flight across the MFMAs
        short8 st0, st1, st2, st3;
        if (kt < 11) {
            size_t kb = (size_t)(kt + 1) * 64 + skc;
            st0 = *(const short8*)(expQ + (size_t)(m0 + sr +  0) * 768 + kb);
            st1 = *(const short8*)(expQ + (size_t)(m0 + sr + 32) * 768 + kb);
            st2 = *(const short8*)(expQ + (size_t)(m0 + sr + 64) * 768 + kb);
            st3 = *(const short8*)(expQ + (size_t)(m0 + sr + 96) * 768 + kb);
        }
        // MFMA phase from As[cur]
        #pragma unroll
        for (int kc = 0; kc < 64; kc += 32) {
            short8 af[4], bfr[4];
            #pragma unroll
            for (int sm = 0; sm < 4; sm++)
                af[sm] = *(const short8*)&As[cur][wm * 64 + sm * 16 + l15][kc + quad * 8];
            #pragma unroll
            for (int sn = 0; sn < 4; sn++) {
                int ncol = n0 + wn * 64 + sn * 16 + l15;
                bfr[sn] = *(const short8*)(Wb + (size_t)ncol * 768 + kt * 64 + kc + quad * 8);
            }
            #pragma unroll
            for (int sm = 0; sm < 4; sm++)
                #pragma unroll
                for (int sn = 0; sn < 4; sn++)
                    acc[sm][sn] = __builtin_amdgcn_mfma_f32_16x16x32_bf16(
                        af[sm], bfr[sn], acc[sm][sn], 0, 0, 0);
        }
        if (kt < 11) {
            int nxt = cur ^ 1;
            // safe to write: all waves finished reading As[nxt] before the
            // barrier at the end of the previous iteration.
            *(short8*)&As[nxt][sr +  0][skc] = st0;
            *(short8*)&As[nxt][sr + 32][skc] = st1;
            *(short8*)&As[nxt][sr + 64][skc] = st2;
            *(short8*)&As[nxt][sr + 96][skc] = st3;
            __syncthreads();
            cur = nxt;
        }
    }

    float bb[4];
    #pragma unroll
    for (int sn = 0; sn < 4; sn++) bb[sn] = brp[n0 + wn * 64 + sn * 16 + l15];
    #pragma unroll
    for (int sm = 0; sm < 4; sm++)
        #pragma unroll
        for (int sn = 0; sn < 4; sn++)
            #pragma unroll
            for (int r = 0; r < 4; r++) {
                int row = m0 + wm * 64 + sm * 16 + quad * 4 + r;
                int col = n0 + wn * 64 + sn * 16 + l15;
                outp[(size_t)row * 256 + col] = acc[sm][sn][r] + bb[sn];
            }
}

// ---------------------------------------------------------------------------
extern "C" void kernel_launch(void* const* d_in, const int* in_sizes, int n_in,
                              void* d_out, int out_size, void* d_ws, size_t ws_size,
                              hipStream_t stream)
{
    (void)in_sizes; (void)n_in; (void)out_size; (void)ws_size;
    const float* f1  = (const float*)d_in[0];
    const float* f2  = (const float*)d_in[1];
    const float* f3  = (const float*)d_in[2];
    const float* f4  = (const float*)d_in[3];
    const float* p1  = (const float*)d_in[4];
    const float* p2  = (const float*)d_in[5];
    const float* p3  = (const float*)d_in[6];
    const float* p4  = (const float*)d_in[7];
    const float* Wq  = (const float*)d_in[8];
    const float* bq  = (const float*)d_in[9];
    const float* Wk  = (const float*)d_in[10];
    const float* bk  = (const float*)d_in[11];
    const float* Wv  = (const float*)d_in[12];
    const float* bv  = (const float*)d_in[13];
    const float* Wrp = (const float*)d_in[14];
    const float* brp = (const float*)d_in[15];

    // workspace layout (total ~52 MB)
    char* ws = (char*)d_ws;
    unsigned short* expQ = (unsigned short*)(ws);                 // 50,331,648
    unsigned short* Wt   = (unsigned short*)(ws + 50331648);      //  1,179,648
    unsigned short* Wtld = (unsigned short*)(ws + 51511296);      //  1,572,864
    float*          ctx  = (float*)(ws + 53084160);               //    393,216
    float*          S    = (float*)(ws + 53477376);               //     12,288

    hipMemsetAsync(ctx, 0, 393216 + 12288, stream);  // ctx + S contiguous

    transpose_w<<<dim3(9, 16), 256, 0, stream>>>(Wq, Wk, Wv, Wt);
    projq_kernel<<<dim3(512), 256, 0, stream>>>(f1, p1, bq, Wt, expQ, S);
    projkv_ctx<<<dim3(512), 512, 0, stream>>>(f2, f3, f4, p2, p3, p4, bk, bv, Wt, ctx);
    wtilde_kernel<<<dim3(96), 256, 0, stream>>>(ctx, S, Wrp, Wtld);
    out_kernel<<<dim3(256, 2), 256, 0, stream>>>(expQ, Wtld, brp, (float*)d_out);
}

// Round 7
// 423.119 us; speedup vs baseline: 1.1200x; 1.0181x over previous
//
#include <hip/hip_runtime.h>
#include <hip/hip_bf16.h>

typedef __attribute__((ext_vector_type(8))) short short8;
typedef __attribute__((ext_vector_type(4))) short shortx4;
typedef __attribute__((ext_vector_type(4))) float floatx4;
typedef __attribute__((ext_vector_type(16))) float floatx16;

#define N_SEQ 8192
#define M_ROWS 32768   // 4*8192

__device__ __forceinline__ unsigned short f2bf(float f) {
    unsigned int x = __builtin_bit_cast(unsigned int, f);
    x += 0x7fff + ((x >> 16) & 1);   // RNE
    return (unsigned short)(x >> 16);
}

// ---------------------------------------------------------------------------
// Kernel 0 (v2): transpose+convert 9 weight matrices [256k x 256n] fp32 ->
// bf16 Wt[job][n][k], LDS-tiled 64x64 so both read and write are coalesced.
__global__ __launch_bounds__(256) void transpose_w(
    const float* __restrict__ Wq, const float* __restrict__ Wk,
    const float* __restrict__ Wv, unsigned short* __restrict__ Wt)
{
    __shared__ unsigned short tile[64][72];
    int job = blockIdx.x;
    int tt = blockIdx.y;
    int k0 = (tt >> 2) * 64, n0 = (tt & 3) * 64;
    const float* src =
        (job < 3) ? (Wq + job * 65536) :
        (job < 6) ? (Wk + (job - 3) * 65536) :
                    (Wv + (job - 6) * 65536);
    int tid = threadIdx.x;
    // phase 1: coalesced read of [k][n] tile, convert, store to LDS
    {
        int r = tid >> 2, cs = (tid & 3) * 16;
        const float* s = src + (size_t)(k0 + r) * 256 + n0 + cs;
        #pragma unroll
        for (int h = 0; h < 2; h++) {
            float4 x0 = *(const float4*)(s + h * 8);
            float4 x1 = *(const float4*)(s + h * 8 + 4);
            short8 v;
            v[0] = (short)f2bf(x0.x); v[1] = (short)f2bf(x0.y);
            v[2] = (short)f2bf(x0.z); v[3] = (short)f2bf(x0.w);
            v[4] = (short)f2bf(x1.x); v[5] = (short)f2bf(x1.y);
            v[6] = (short)f2bf(x1.z); v[7] = (short)f2bf(x1.w);
            *(short8*)&tile[r][cs + h * 8] = v;
        }
    }
    __syncthreads();
    // phase 2: gather transposed from LDS, coalesced write of [n][k]
    {
        int rn = tid >> 2, ks = (tid & 3) * 16;
        unsigned short tmp[16];
        #pragma unroll
        for (int q = 0; q < 16; q++) tmp[q] = tile[ks + q][rn];
        short8 v0, v1;
        #pragma unroll
        for (int q = 0; q < 8; q++) { v0[q] = (short)tmp[q]; v1[q] = (short)tmp[q + 8]; }
        unsigned short* dst = Wt + (size_t)job * 65536 + (size_t)(n0 + rn) * 256 + k0 + ks;
        *(short8*)dst = v0;
        *(short8*)(dst + 8) = v1;
    }
}

// ---------------------------------------------------------------------------
// Kernel 1 (v5): Q projection, ROW-split. Grid 1024 x 256 thr: 32-row tiles,
// 4 waves each owning a 32-col quarter of each 128-col n-tile (6 n-tiles =
// 3 branches x 2). No staging duplication (f1/p1 read once); weights are
// L2-resident so their 2x re-read is free. LDS 16.5 KB -> 4 blocks/CU
// (grid-limited) x 4 waves = 16 waves/CU, 2x the old residency.
__global__ __launch_bounds__(256) void projq_kernel(
    const float* __restrict__ f1, const float* __restrict__ p1,
    const float* __restrict__ bq, const unsigned short* __restrict__ Wt,
    unsigned short* __restrict__ expQ, float* __restrict__ S)
{
    __shared__ __align__(16) unsigned short As[32][264];
    int m0 = blockIdx.x * 32;
    int b = m0 >> 13;
    int tid = threadIdx.x;
    int lane = tid & 63, wave = tid >> 6;   // 4 waves, 32-col quarters
    int quad = lane >> 4, l15 = lane & 15;

    // stage A = bf16(f1 + p1): 32 rows x 8 segs of 32 cols
    {
        int row = tid >> 3, seg = tid & 7;
        const float* fr = f1 + (size_t)(m0 + row) * 256 + seg * 32;
        const float* pr = p1 + (size_t)(m0 + row) * 256 + seg * 32;
        #pragma unroll
        for (int q = 0; q < 4; q++) {
            float4 x0 = *(const float4*)(fr + q * 8);
            float4 x1 = *(const float4*)(fr + q * 8 + 4);
            float4 y0 = *(const float4*)(pr + q * 8);
            float4 y1 = *(const float4*)(pr + q * 8 + 4);
            short8 v;
            v[0] = (short)f2bf(x0.x + y0.x); v[1] = (short)f2bf(x0.y + y0.y);
            v[2] = (short)f2bf(x0.z + y0.z); v[3] = (short)f2bf(x0.w + y0.w);
            v[4] = (short)f2bf(x1.x + y1.x); v[5] = (short)f2bf(x1.y + y1.y);
            v[6] = (short)f2bf(x1.z + y1.z); v[7] = (short)f2bf(x1.w + y1.w);
            *(short8*)&As[row][seg * 32 + q * 8] = v;
        }
    }
    __syncthreads();

    for (int nj = 0; nj < 6; nj++) {
        int j = nj >> 1;
        int n0 = (nj & 1) * 128;
        const unsigned short* Wj = Wt + (size_t)j * 65536;

        floatx4 acc[2][2];
        #pragma unroll
        for (int sm = 0; sm < 2; sm++)
            #pragma unroll
            for (int sn = 0; sn < 2; sn++)
                #pragma unroll
                for (int r = 0; r < 4; r++) acc[sm][sn][r] = 0.0f;

        #pragma unroll
        for (int ks = 0; ks < 8; ks++) {
            short8 af[2], bfr[2];
            #pragma unroll
            for (int sm = 0; sm < 2; sm++)
                af[sm] = *(const short8*)&As[sm * 16 + l15][ks * 32 + quad * 8];
            #pragma unroll
            for (int sn = 0; sn < 2; sn++) {
                int ncol = n0 + wave * 32 + sn * 16 + l15;
                bfr[sn] = *(const short8*)(Wj + (size_t)ncol * 256 + ks * 32 + quad * 8);
            }
            #pragma unroll
            for (int sm = 0; sm < 2; sm++)
                #pragma unroll
                for (int sn = 0; sn < 2; sn++)
                    acc[sm][sn] = __builtin_amdgcn_mfma_f32_16x16x32_bf16(
                        af[sm], bfr[sn], acc[sm][sn], 0, 0, 0);
        }

        float colsum[2] = {0.f, 0.f};
        #pragma unroll
        for (int sm = 0; sm < 2; sm++)
            #pragma unroll
            for (int sn = 0; sn < 2; sn++) {
                float bb = bq[j * 256 + n0 + wave * 32 + sn * 16 + l15];
                #pragma unroll
                for (int r = 0; r < 4; r++) {
                    float e = __expf(acc[sm][sn][r] + bb);
                    colsum[sn] += e;
                    int row = m0 + sm * 16 + quad * 4 + r;
                    int col = j * 256 + n0 + wave * 32 + sn * 16 + l15;
                    expQ[(size_t)row * 768 + col] = f2bf(e);
                }
            }
        #pragma unroll
        for (int sn = 0; sn < 2; sn++) {
            float v = colsum[sn];
            v += __shfl_xor(v, 16, 64);
            v += __shfl_xor(v, 32, 64);
            if (quad == 0)
                atomicAdd(&S[b * 768 + j * 256 + n0 + wave * 32 + sn * 16 + l15], v);
        }
    }
}

// ---------------------------------------------------------------------------
// Kernel 2 (R1 v2, best known): fused K/V projection + softmax(K) + ctx.
// Grid: 512 x 512 thr (8 waves). 3 x 64-row tiles per block. One head per
// wave. K_s/V_s parked transposed bf16 in LDS (stride 72). ctx in regs,
// fp32 atomics on flush.
__global__ __launch_bounds__(512, 4) void projkv_ctx(
    const float* __restrict__ f2, const float* __restrict__ f3, const float* __restrict__ f4,
    const float* __restrict__ p2, const float* __restrict__ p3, const float* __restrict__ p4,
    const float* __restrict__ bk, const float* __restrict__ bv,
    const unsigned short* __restrict__ Wt, float* __restrict__ ctx)
{
    __shared__ __align__(16) unsigned short sh[36864];

    int tid = threadIdx.x;
    int lane = tid & 63, wn = tid >> 6;     // 8 waves; wave wn owns head wn
    int quad = lane >> 4, l15 = lane & 15;
    int srow = tid >> 3, seg = tid & 7;     // staging: 64 rows x 8 segs

    int gbase = -1;
    int cur_ib = -1;
    const float *fin = nullptr, *pin = nullptr;
    const unsigned short *Wk_ = nullptr, *Wv_ = nullptr;
    float bkk[2] = {0.f, 0.f}, bvv[2] = {0.f, 0.f};
    floatx16 ctxacc;

    for (int j = 0; j < 3; j++) {
        int tau = blockIdx.x * 3 + j;       // global 64-row tile index, [0,1536)
        int ib = tau >> 7;                  // (i,b) pair, 128 tiles each
        if (ib != cur_ib) {
            if (gbase >= 0) {               // flush previous (i,b) accumulation
                int d = lane & 31;
                #pragma unroll
                for (int reg = 0; reg < 16; reg++) {
                    int cc = (reg & 3) + 8 * (reg >> 2) + 4 * (lane >> 5);
                    atomicAdd(&ctx[(size_t)gbase * 1024 + cc * 32 + d], ctxacc[reg]);
                }
            }
            cur_ib = ib;
            int b = ib & 3, i = ib >> 2;
            fin = ((i == 0) ? f2 : (i == 1) ? f3 : f4) + (size_t)b * N_SEQ * 256;
            pin = ((i == 0) ? p2 : (i == 1) ? p3 : p4) + (size_t)b * N_SEQ * 256;
            Wk_ = Wt + (size_t)(3 + i) * 65536;
            Wv_ = Wt + (size_t)(6 + i) * 65536;
            #pragma unroll
            for (int sn = 0; sn < 2; sn++) {
                bkk[sn] = bk[i * 256 + wn * 32 + sn * 16 + l15];
                bvv[sn] = bv[i * 256 + wn * 32 + sn * 16 + l15];
            }
            gbase = i * 32 + b * 8 + wn;
            #pragma unroll
            for (int q = 0; q < 16; q++) ctxacc[q] = 0.0f;
        }
        int m0 = (tau & 127) * 64;

        __syncthreads();   // previous tile's KT/VT reads done before staging overwrites
        // stage AK = bf16(f+p), AV = bf16(f)
        {
            const float* fr = fin + (size_t)(m0 + srow) * 256;
            const float* pr = pin + (size_t)(m0 + srow) * 256;
            #pragma unroll
            for (int q = 0; q < 4; q++) {
                int c0 = q * 64 + seg * 8;
                float4 x0 = *(const float4*)(fr + c0);
                float4 x1 = *(const float4*)(fr + c0 + 4);
                float4 y0 = *(const float4*)(pr + c0);
                float4 y1 = *(const float4*)(pr + c0 + 4);
                short8 vv, kk;
                vv[0] = (short)f2bf(x0.x); kk[0] = (short)f2bf(x0.x + y0.x);
                vv[1] = (short)f2bf(x0.y); kk[1] = (short)f2bf(x0.y + y0.y);
                vv[2] = (short)f2bf(x0.z); kk[2] = (short)f2bf(x0.z + y0.z);
                vv[3] = (short)f2bf(x0.w); kk[3] = (short)f2bf(x0.w + y0.w);
                vv[4] = (short)f2bf(x1.x); kk[4] = (short)f2bf(x1.x + y1.x);
                vv[5] = (short)f2bf(x1.y); kk[5] = (short)f2bf(x1.y + y1.y);
                vv[6] = (short)f2bf(x1.z); kk[6] = (short)f2bf(x1.z + y1.z);
                vv[7] = (short)f2bf(x1.w); kk[7] = (short)f2bf(x1.w + y1.w);
                *(short8*)&sh[srow * 264 + c0] = kk;
                *(short8*)&sh[18432 + srow * 264 + c0] = vv;
            }
        }
        __syncthreads();

        // ---- K GEMM: 64 rows x 32 cols per wave
        floatx4 acc[4][2];
        #pragma unroll
        for (int sm = 0; sm < 4; sm++)
            #pragma unroll
            for (int sn = 0; sn < 2; sn++)
                #pragma unroll
                for (int r = 0; r < 4; r++) acc[sm][sn][r] = 0.0f;
        #pragma unroll
        for (int ks = 0; ks < 8; ks++) {
            short8 af[4], bfr[2];
            #pragma unroll
            for (int sm = 0; sm < 4; sm++)
                af[sm] = *(const short8*)&sh[(sm * 16 + l15) * 264 + ks * 32 + quad * 8];
            #pragma unroll
            for (int sn = 0; sn < 2; sn++) {
                int ncol = wn * 32 + sn * 16 + l15;
                bfr[sn] = *(const short8*)(Wk_ + (size_t)ncol * 256 + ks * 32 + quad * 8);
            }
            #pragma unroll
            for (int sm = 0; sm < 4; sm++)
                #pragma unroll
                for (int sn = 0; sn < 2; sn++)
                    acc[sm][sn] = __builtin_amdgcn_mfma_f32_16x16x32_bf16(
                        af[sm], bfr[sn], acc[sm][sn], 0, 0, 0);
        }
        // per-row softmax over this wave's head (32 cols)
        #pragma unroll
        for (int sm = 0; sm < 4; sm++)
            #pragma unroll
            for (int r = 0; r < 4; r++) {
                float e0 = __expf(acc[sm][0][r] + bkk[0]);
                float e1 = __expf(acc[sm][1][r] + bkk[1]);
                float t = e0 + e1;
                t += __shfl_xor(t, 1, 64);
                t += __shfl_xor(t, 2, 64);
                t += __shfl_xor(t, 4, 64);
                t += __shfl_xor(t, 8, 64);
                float inv = 1.0f / t;
                acc[sm][0][r] = e0 * inv;
                acc[sm][1][r] = e1 * inv;
            }
        __syncthreads();   // all waves done reading AK (region0)
        // park K_s transposed: KT[col][n], packed 4 rows per ds_write_b64
        #pragma unroll
        for (int sm = 0; sm < 4; sm++)
            #pragma unroll
            for (int sn = 0; sn < 2; sn++) {
                shortx4 v;
                #pragma unroll
                for (int r = 0; r < 4; r++) v[r] = (short)f2bf(acc[sm][sn][r]);
                *(shortx4*)&sh[(wn * 32 + sn * 16 + l15) * 72 + sm * 16 + quad * 4] = v;
            }

        // ---- V GEMM from AV (region1, untouched by KT park)
        #pragma unroll
        for (int sm = 0; sm < 4; sm++)
            #pragma unroll
            for (int sn = 0; sn < 2; sn++)
                #pragma unroll
                for (int r = 0; r < 4; r++) acc[sm][sn][r] = 0.0f;
        #pragma unroll
        for (int ks = 0; ks < 8; ks++) {
            short8 af[4], bfr[2];
            #pragma unroll
            for (int sm = 0; sm < 4; sm++)
                af[sm] = *(const short8*)&sh[18432 + (sm * 16 + l15) * 264 + ks * 32 + quad * 8];
            #pragma unroll
            for (int sn = 0; sn < 2; sn++) {
                int ncol = wn * 32 + sn * 16 + l15;
                bfr[sn] = *(const short8*)(Wv_ + (size_t)ncol * 256 + ks * 32 + quad * 8);
            }
            #pragma unroll
            for (int sm = 0; sm < 4; sm++)
                #pragma unroll
                for (int sn = 0; sn < 2; sn++)
                    acc[sm][sn] = __builtin_amdgcn_mfma_f32_16x16x32_bf16(
                        af[sm], bfr[sn], acc[sm][sn], 0, 0, 0);
        }
        __syncthreads();   // all waves done reading AV (region1)
        // park V transposed (+bias): VT[col][n] (wave-local consumption)
        #pragma unroll
        for (int sm = 0; sm < 4; sm++)
            #pragma unroll
            for (int sn = 0; sn < 2; sn++) {
                shortx4 v;
                #pragma unroll
                for (int r = 0; r < 4; r++) v[r] = (short)f2bf(acc[sm][sn][r] + bvv[sn]);
                *(shortx4*)&sh[18432 + (wn * 32 + sn * 16 + l15) * 72 + sm * 16 + quad * 4] = v;
            }

        // ---- ctx for head wn: D[c][d] += sum_n K_s[n][c] * V_s[n][d]
        {
            int hc = wn * 32 + (lane & 31);
            int nb = (lane >> 5) * 8;
            #pragma unroll
            for (int s = 0; s < 4; s++) {
                short8 afr  = *(const short8*)&sh[hc * 72 + s * 16 + nb];
                short8 bfr2 = *(const short8*)&sh[18432 + hc * 72 + s * 16 + nb];
                ctxacc = __builtin_amdgcn_mfma_f32_32x32x16_bf16(afr, bfr2, ctxacc, 0, 0, 0);
            }
        }
    }

    // final flush
    if (gbase >= 0) {
        int d = lane & 31;
        #pragma unroll
        for (int reg = 0; reg < 16; reg++) {
            int cc = (reg & 3) + 8 * (reg >> 2) + 4 * (lane >> 5);
            atomicAdd(&ctx[(size_t)gbase * 1024 + cc * 32 + d], ctxacc[reg]);
        }
    }
}

// ---------------------------------------------------------------------------
// Kernel 3: Wtld[b][e][i*256+h*32+c] = sum_d (ctx[g][c][d]/S[b][i*256+h*32+c]) * Wrp[i*256+h*32+d][e]
__global__ __launch_bounds__(256) void wtilde_kernel(
    const float* __restrict__ ctx, const float* __restrict__ S,
    const float* __restrict__ Wrp, unsigned short* __restrict__ Wtld)
{
    __shared__ float cp[1024];
    int g = blockIdx.x;  // i*32 + b*8 + h
    int i = g >> 5, b = (g >> 3) & 3, h = g & 7;
    int t = threadIdx.x;
    #pragma unroll
    for (int q = 0; q < 4; q++) {
        int idx = t + q * 256;
        int c = idx >> 5;
        cp[idx] = ctx[(size_t)g * 1024 + idx] / S[b * 768 + i * 256 + h * 32 + c];
    }
    __syncthreads();
    float accv[32];
    #pragma unroll
    for (int c = 0; c < 32; c++) accv[c] = 0.0f;
    for (int d = 0; d < 32; d++) {
        float w = Wrp[(size_t)(i * 256 + h * 32 + d) * 256 + t];
        #pragma unroll
        for (int c = 0; c < 32; c++) accv[c] += cp[c * 32 + d] * w;
    }
    for (int c = 0; c < 32; c++)
        Wtld[((size_t)b * 256 + t) * 768 + i * 256 + h * 32 + c] = f2bf(accv[c]);
}

// ---------------------------------------------------------------------------
// Kernel 4 (R6 v5, kept): out[b] = expQ[b] @ Wtld[b]^T + brp. 128x128 tiles,
// double-buffered LDS pipeline, one barrier per kt. LDS 73.7 KB.
__global__ __launch_bounds__(256) void out_kernel(
    const unsigned short* __restrict__ expQ, const unsigned short* __restrict__ Wtld,
    const float* __restrict__ brp, float* __restrict__ outp)
{
    __shared__ __align__(16) unsigned short As[2][128][72];
    int m0 = blockIdx.x * 128;
    int n0 = blockIdx.y * 128;
    int b = m0 >> 13;
    const unsigned short* Wb = Wtld + (size_t)b * 256 * 768;
    int tid = threadIdx.x;
    int lane = tid & 63, wave = tid >> 6;
    int wm = wave >> 1, wn = wave & 1;
    int quad = lane >> 4, l15 = lane & 15;
    int sr = tid >> 3, skc = (tid & 7) * 8;

    floatx4 acc[4][4];
    #pragma unroll
    for (int a = 0; a < 4; a++)
        #pragma unroll
        for (int cc = 0; cc < 4; cc++)
            #pragma unroll
            for (int r = 0; r < 4; r++) acc[a][cc][r] = 0.0f;

    // prologue: stage kt=0 into buffer 0
    {
        short8 st0, st1, st2, st3;
        st0 = *(const short8*)(expQ + (size_t)(m0 + sr +  0) * 768 + skc);
        st1 = *(const short8*)(expQ + (size_t)(m0 + sr + 32) * 768 + skc);
        st2 = *(const short8*)(expQ + (size_t)(m0 + sr + 64) * 768 + skc);
        st3 = *(const short8*)(expQ + (size_t)(m0 + sr + 96) * 768 + skc);
        *(short8*)&As[0][sr +  0][skc] = st0;
        *(short8*)&As[0][sr + 32][skc] = st1;
        *(short8*)&As[0][sr + 64][skc] = st2;
        *(short8*)&As[0][sr + 96][skc] = st3;
    }
    __syncthreads();

    int cur = 0;
    for (int kt = 0; kt < 12; kt++) {
        short8 st0, st1, st2, st3;
        if (kt < 11) {
            size_t kb = (size_t)(kt + 1) * 64 + skc;
            st0 = *(const short8*)(expQ + (size_t)(m0 + sr +  0) * 768 + kb);
            st1 = *(const short8*)(expQ + (size_t)(m0 + sr + 32) * 768 + kb);
            st2 = *(const short8*)(expQ + (size_t)(m0 + sr + 64) * 768 + kb);
            st3 = *(const short8*)(expQ + (size_t)(m0 + sr + 96) * 768 + kb);
        }
        #pragma unroll
        for (int kc = 0; kc < 64; kc += 32) {
            short8 af[4], bfr[4];
            #pragma unroll
            for (int sm = 0; sm < 4; sm++)
                af[sm] = *(const short8*)&As[cur][wm * 64 + sm * 16 + l15][kc + quad * 8];
            #pragma unroll
            for (int sn = 0; sn < 4; sn++) {
                int ncol = n0 + wn * 64 + sn * 16 + l15;
                bfr[sn] = *(const short8*)(Wb + (size_t)ncol * 768 + kt * 64 + kc + quad * 8);
            }
            #pragma unroll
            for (int sm = 0; sm < 4; sm++)
                #pragma unroll
                for (int sn = 0; sn < 4; sn++)
                    acc[sm][sn] = __builtin_amdgcn_mfma_f32_16x16x32_bf16(
                        af[sm], bfr[sn], acc[sm][sn], 0, 0, 0);
        }
        if (kt < 11) {
            int nxt = cur ^ 1;
            *(short8*)&As[nxt][sr +  0][skc] = st0;
            *(short8*)&As[nxt][sr + 32][skc] = st1;
            *(short8*)&As[nxt][sr + 64][skc] = st2;
            *(short8*)&As[nxt][sr + 96][skc] = st3;
            __syncthreads();
            cur = nxt;
        }
    }

    float bb[4];
    #pragma unroll
    for (int sn = 0; sn < 4; sn++) bb[sn] = brp[n0 + wn * 64 + sn * 16 + l15];
    #pragma unroll
    for (int sm = 0; sm < 4; sm++)
        #pragma unroll
        for (int sn = 0; sn < 4; sn++)
            #pragma unroll
            for (int r = 0; r < 4; r++) {
                int row = m0 + wm * 64 + sm * 16 + quad * 4 + r;
                int col = n0 + wn * 64 + sn * 16 + l15;
                outp[(size_t)row * 256 + col] = acc[sm][sn][r] + bb[sn];
            }
}

// ---------------------------------------------------------------------------
extern "C" void kernel_launch(void* const* d_in, const int* in_sizes, int n_in,
                              void* d_out, int out_size, void* d_ws, size_t ws_size,
                              hipStream_t stream)
{
    (void)in_sizes; (void)n_in; (void)out_size; (void)ws_size;
    const float* f1  = (const float*)d_in[0];
    const float* f2  = (const float*)d_in[1];
    const float* f3  = (const float*)d_in[2];
    const float* f4  = (const float*)d_in[3];
    const float* p1  = (const float*)d_in[4];
    const float* p2  = (const float*)d_in[5];
    const float* p3  = (const float*)d_in[6];
    const float* p4  = (const float*)d_in[7];
    const float* Wq  = (const float*)d_in[8];
    const float* bq  = (const float*)d_in[9];
    const float* Wk  = (const float*)d_in[10];
    const float* bk  = (const float*)d_in[11];
    const float* Wv  = (const float*)d_in[12];
    const float* bv  = (const float*)d_in[13];
    const float* Wrp = (const float*)d_in[14];
    const float* brp = (const float*)d_in[15];

    // workspace layout (total ~52 MB)
    char* ws = (char*)d_ws;
    unsigned short* expQ = (unsigned short*)(ws);                 // 50,331,648
    unsigned short* Wt   = (unsigned short*)(ws + 50331648);      //  1,179,648
    unsigned short* Wtld = (unsigned short*)(ws + 51511296);      //  1,572,864
    float*          ctx  = (float*)(ws + 53084160);               //    393,216
    float*          S    = (float*)(ws + 53477376);               //     12,288

    hipMemsetAsync(ctx, 0, 393216 + 12288, stream);  // ctx + S contiguous

    transpose_w<<<dim3(9, 16), 256, 0, stream>>>(Wq, Wk, Wv, Wt);
    projq_kernel<<<dim3(1024), 256, 0, stream>>>(f1, p1, bq, Wt, expQ, S);
    projkv_ctx<<<dim3(512), 512, 0, stream>>>(f2, f3, f4, p2, p3, p4, bk, bv, Wt, ctx);
    wtilde_kernel<<<dim3(96), 256, 0, stream>>>(ctx, S, Wrp, Wtld);
    out_kernel<<<dim3(256, 2), 256, 0, stream>>>(expQ, Wtld, brp, (float*)d_out);
}